// Round 4
// baseline (166.454 us; speedup 1.0000x reference)
//
#include <hip/hip_runtime.h>

// SNN forward — R8: R7 structure + occupancy fix + common-case zero fastpath.
//
// R7 post-mortem: 67us, occupancy 24% (40KB LDS -> 4 blocks/CU), VALU 29%,
// HBM 19%, conflicts 0 -> latency-bound, too few waves. R8:
//  - RPL 4->2: per-wave LDS 10KB->5KB, block 20KB -> 8 blocks/CU = 32
//    waves/CU (VGPR ~50 allows 8 waves/SIMD). 2x waves, half-size each.
//  - common case (no dense row in wave, ~91%): store zero v4f directly,
//    skipping LDS zero-fill + readback entirely. Dense-wave case keeps the
//    LDS stage (wave-private LDS ops are in-order; no barrier needed).
//
// Exactness (absmax 0.0 across R4-R7):
//  - layer-1 packed v2f chain (mul,+,+,+,+ in k-order) verbatim from R6/R7.
//  - gates: popc(m)*mxmax < 1.998 and S=sum smx[i] < 1.998 imply reference
//    h2[j] < 2.0 (fp sum err <= 31*2^-24*Sum|terms| ~ 4e-5 << margin).
//  - dense fallback: verbatim ascending set-bit order.

typedef float v4f __attribute__((ext_vector_type(4)));
typedef float v2f __attribute__((ext_vector_type(2)));

#define TPB 256
#define RPL 2                  // rows per lane
#define WROWS (64 * RPL)       // 128 rows per wave
#define RPB (TPB * RPL)        // 512 rows per block

// ---- prep (1 block, once per replay): verified R6/R7 ----
// ws[0..159]  = W1^T as [5][32] floats (pairs adjacent -> v2f loads)
// ws[160..191]= smx[i] = max_j W2[j][i];  ws[192] = mxmax
__global__ __launch_bounds__(64) void snn_prep(
    const float* __restrict__ W1,   // [32,5]
    const float* __restrict__ W2,   // [32,32]
    float* __restrict__ ws)
{
    const int t = threadIdx.x;      // 0..63
    float mm = -3.4e38f;
    if (t < 32) {
#pragma unroll
        for (int k = 0; k < 5; ++k) ws[k * 32 + t] = W1[t * 5 + k];
        mm = W2[t];
#pragma unroll
        for (int j = 1; j < 32; ++j) mm = fmaxf(mm, W2[j * 32 + t]);
        ws[160 + t] = mm;
    }
#pragma unroll
    for (int off = 32; off; off >>= 1) mm = fmaxf(mm, __shfl_xor(mm, off));
    if (t == 0) ws[192] = mm;
}

__global__ __launch_bounds__(TPB) void snn_fused(
    const float* __restrict__ x,
    const float* __restrict__ W2,   // [32,32]
    const float* __restrict__ W3,   // [16,32]
    const float* __restrict__ W4,   // [10,16]
    const float* __restrict__ ws,
    float* __restrict__ out,        // [B,10]
    int B)
{
    __shared__ __align__(16) float stage[4][WROWS * 10];   // 20KB, 5KB/wave

    const int t = threadIdx.x;
    const int wv = t >> 6, lane = t & 63;
    float* sbuf = stage[wv];
    const long wrow0 = (long)blockIdx.x * RPB + (long)wv * WROWS;
    if (wrow0 >= B) return;

    const v2f* __restrict__ w1p = (const v2f*)ws;   // [5][16] neuron-pairs
    const float* __restrict__ smx = ws + 160;
    const float mxmax = ws[192];

    if (wrow0 + WROWS <= B) {
        // ---- coalesced x stage: 640 floats = 160 v4f, intra-wave only ----
        const v4f* xg = (const v4f*)(x + wrow0 * 5);
        v4f* s4 = (v4f*)sbuf;
#pragma unroll
        for (int e = 0; e < 3; ++e) {
            int idx = e * 64 + lane;
            if (idx < (WROWS * 5) / 4) s4[idx] = xg[idx];
        }

        // own 10 x floats back (lane*40B, v2f reads)
        v2f xp[5];
        {
            const v2f* sx = (const v2f*)(sbuf + lane * 10);
#pragma unroll
            for (int e = 0; e < 5; ++e) xp[e] = sx[e];
        }
        const float* xf = (const float*)xp;

        // ---- layer 1: j2-outer (uniform weights amortized over rows) ----
        unsigned m[RPL] = {0u, 0u};
#pragma unroll
        for (int j2 = 0; j2 < 16; ++j2) {
            const v2f wa = w1p[j2], wb = w1p[16 + j2], wc = w1p[32 + j2];
            const v2f wd = w1p[48 + j2], we = w1p[64 + j2];
#pragma unroll
            for (int c = 0; c < RPL; ++c) {
                v2f h = xf[c * 5 + 0] * wa;   // exact per-neuron chain order
                h += xf[c * 5 + 1] * wb;
                h += xf[c * 5 + 2] * wc;
                h += xf[c * 5 + 3] * wd;
                h += xf[c * 5 + 4] * we;
                if (h.x >= 2.0f) m[c] |= (1u << (2 * j2));
                if (h.y >= 2.0f) m[c] |= (1u << (2 * j2 + 1));
            }
        }

        // ---- gates; note whether this lane produced any dense row ----
        bool dense[RPL];
        unsigned m2s[RPL];
        bool any_dense = false;
#pragma unroll
        for (int c = 0; c < RPL; ++c) {
            dense[c] = false;
            m2s[c] = 0u;
            const unsigned mc = m[c];
            if (mc && ((float)__popc(mc) * mxmax >= 1.998f)) {
                float S = 0.0f;
                unsigned mm = mc;
                while (mm) { int i = __ffs(mm) - 1; mm &= mm - 1; S += smx[i]; }
                if (S >= 1.998f) {
                    // dense layer 2: VERBATIM verified ascending set-bit order
                    float h2[32];
#pragma unroll
                    for (int j = 0; j < 32; ++j) h2[j] = 0.0f;
                    mm = mc;
                    while (mm) {
                        const int i = __ffs(mm) - 1;
                        mm &= mm - 1;
                        const float* col = W2 + i;   // W2^T[i][j] == W2[j*32+i]
#pragma unroll
                        for (int j = 0; j < 32; ++j) h2[j] += col[j * 32];
                    }
                    unsigned m2 = 0u;
#pragma unroll
                    for (int j = 0; j < 32; ++j)
                        if (h2[j] >= 2.0f) m2 |= (1u << j);
                    m2s[c] = m2;
                    if (m2) { dense[c] = true; any_dense = true; }
                }
            }
        }

        if (!__any(any_dense)) {
            // ---- common case (~91% of waves): pure-zero coalesced store ----
            v4f z = {0.0f, 0.0f, 0.0f, 0.0f};
            v4f* og = (v4f*)(out + wrow0 * 10);
#pragma unroll
            for (int e = 0; e < 5; ++e)
                __builtin_nontemporal_store(z, &og[e * 64 + lane]);
        } else {
            // ---- rare: zero-fill LDS, dense lanes overwrite, flush ----
            {
                v4f z = {0.0f, 0.0f, 0.0f, 0.0f};
#pragma unroll
                for (int e = 0; e < 5; ++e) s4[e * 64 + lane] = z;
            }
#pragma unroll
            for (int c = 0; c < RPL; ++c) {
                if (!dense[c]) continue;
                const unsigned m2 = m2s[c];
                unsigned m3 = 0u;
#pragma unroll
                for (int j = 0; j < 16; ++j) {
                    float g = 0.0f;
#pragma unroll
                    for (int i = 0; i < 32; ++i)
                        if ((m2 >> i) & 1u) g += W3[j * 32 + i];
                    if (g >= 2.0f) m3 |= (1u << j);
                }
                float* orow = sbuf + (lane * RPL + c) * 10;
#pragma unroll
                for (int j = 0; j < 10; ++j) {
                    float g = 0.0f;
#pragma unroll
                    for (int i = 0; i < 16; ++i)
                        if ((m3 >> i) & 1u) g += W4[j * 16 + i];
                    orow[j] = (g >= 2.0f) ? 1.0f : 0.0f;
                }
            }
            v4f* og = (v4f*)(out + wrow0 * 10);
            const v4f* s4c = (const v4f*)sbuf;
#pragma unroll
            for (int e = 0; e < 5; ++e)
                __builtin_nontemporal_store(s4c[e * 64 + lane], &og[e * 64 + lane]);
        }
    } else {
        // ---- tail (not hit at B=2^21; correctness-general) ----
        for (int c = 0; c < RPL; ++c) {
            const long r = wrow0 + (long)lane * RPL + c;
            if (r >= B) continue;
            float xr[5];
#pragma unroll
            for (int k = 0; k < 5; ++k) xr[k] = x[r * 5 + k];
            unsigned mc = 0u;
#pragma unroll
            for (int j2 = 0; j2 < 16; ++j2) {
                v2f h = xr[0] * w1p[j2];
                h += xr[1] * w1p[16 + j2];
                h += xr[2] * w1p[32 + j2];
                h += xr[3] * w1p[48 + j2];
                h += xr[4] * w1p[64 + j2];
                if (h.x >= 2.0f) mc |= (1u << (2 * j2));
                if (h.y >= 2.0f) mc |= (1u << (2 * j2 + 1));
            }
            float o[10];
#pragma unroll
            for (int j = 0; j < 10; ++j) o[j] = 0.0f;
            if (mc && ((float)__popc(mc) * mxmax >= 1.998f)) {
                float S = 0.0f;
                unsigned mm = mc;
                while (mm) { int i = __ffs(mm) - 1; mm &= mm - 1; S += smx[i]; }
                if (S >= 1.998f) {
                    float h2[32];
#pragma unroll
                    for (int j = 0; j < 32; ++j) h2[j] = 0.0f;
                    mm = mc;
                    while (mm) {
                        const int i = __ffs(mm) - 1;
                        mm &= mm - 1;
                        const float* col = W2 + i;
#pragma unroll
                        for (int j = 0; j < 32; ++j) h2[j] += col[j * 32];
                    }
                    unsigned m2 = 0u;
#pragma unroll
                    for (int j = 0; j < 32; ++j)
                        if (h2[j] >= 2.0f) m2 |= (1u << j);
                    if (m2) {
                        unsigned m3 = 0u;
#pragma unroll
                        for (int j = 0; j < 16; ++j) {
                            float g = 0.0f;
#pragma unroll
                            for (int i = 0; i < 32; ++i)
                                if ((m2 >> i) & 1u) g += W3[j * 32 + i];
                            if (g >= 2.0f) m3 |= (1u << j);
                        }
#pragma unroll
                        for (int j = 0; j < 10; ++j) {
                            float g = 0.0f;
#pragma unroll
                            for (int i = 0; i < 16; ++i)
                                if ((m3 >> i) & 1u) g += W4[j * 16 + i];
                            o[j] = (g >= 2.0f) ? 1.0f : 0.0f;
                        }
                    }
                }
            }
#pragma unroll
            for (int j = 0; j < 10; ++j) out[r * 10 + j] = o[j];
        }
    }
}

extern "C" void kernel_launch(void* const* d_in, const int* in_sizes, int n_in,
                              void* d_out, int out_size, void* d_ws, size_t ws_size,
                              hipStream_t stream) {
    const float* x  = (const float*)d_in[0];
    const float* W1 = (const float*)d_in[1];
    const float* W2 = (const float*)d_in[2];
    const float* W3 = (const float*)d_in[3];
    const float* W4 = (const float*)d_in[4];
    float* out = (float*)d_out;
    float* ws  = (float*)d_ws;

    int B = in_sizes[0] / 5;
    snn_prep<<<1, 64, 0, stream>>>(W1, W2, ws);
    int grid = (B + RPB - 1) / RPB;
    snn_fused<<<grid, TPB, 0, stream>>>(x, W2, W3, W4, ws, out, B);
}

// Round 5
// 165.919 us; speedup vs baseline: 1.0032x; 1.0032x over previous
//
#include <hip/hip_runtime.h>

// SNN forward — R9: R8 verbatim, with ONE change: plain cached stores
// instead of __builtin_nontemporal_store.
//
// Rationale: across R4-R8, wall time is pinned at 67-90us regardless of
// barriers (R4/R5 vs R7/R8), LDS size, RPL, or occupancy (24-61%), while
// derived write BW is always ~1.2-1.5 TB/s. NT stores (used in EVERY
// round, never ablated) force the 80MB output stream to drain toward HBM
// inside the kernel instead of being absorbed by L2(32MB)/MALL(256MB) --
// out+x = 120MB fits in L3 entirely. Hypothesis: the NT drain rate IS the
// ~60us floor. R9 is the clean A/B.
//
// Exactness (absmax 0.0 across R4-R8): layer-1 packed v2f chain, gates
// (popc(m)*mxmax < 1.998, S=sum smx[i] < 1.998; fp sum err ~4e-5 <<
// margin), dense fallback in ascending set-bit order -- all byte-identical
// to R8. Stores don't affect numerics.

typedef float v4f __attribute__((ext_vector_type(4)));
typedef float v2f __attribute__((ext_vector_type(2)));

#define TPB 256
#define RPL 2                  // rows per lane
#define WROWS (64 * RPL)       // 128 rows per wave
#define RPB (TPB * RPL)        // 512 rows per block

// ---- prep (1 block, once per replay): verified R6-R8 ----
// ws[0..159]  = W1^T as [5][32] floats (pairs adjacent -> v2f loads)
// ws[160..191]= smx[i] = max_j W2[j][i];  ws[192] = mxmax
__global__ __launch_bounds__(64) void snn_prep(
    const float* __restrict__ W1,   // [32,5]
    const float* __restrict__ W2,   // [32,32]
    float* __restrict__ ws)
{
    const int t = threadIdx.x;      // 0..63
    float mm = -3.4e38f;
    if (t < 32) {
#pragma unroll
        for (int k = 0; k < 5; ++k) ws[k * 32 + t] = W1[t * 5 + k];
        mm = W2[t];
#pragma unroll
        for (int j = 1; j < 32; ++j) mm = fmaxf(mm, W2[j * 32 + t]);
        ws[160 + t] = mm;
    }
#pragma unroll
    for (int off = 32; off; off >>= 1) mm = fmaxf(mm, __shfl_xor(mm, off));
    if (t == 0) ws[192] = mm;
}

__global__ __launch_bounds__(TPB) void snn_fused(
    const float* __restrict__ x,
    const float* __restrict__ W2,   // [32,32]
    const float* __restrict__ W3,   // [16,32]
    const float* __restrict__ W4,   // [10,16]
    const float* __restrict__ ws,
    float* __restrict__ out,        // [B,10]
    int B)
{
    __shared__ __align__(16) float stage[4][WROWS * 10];   // 20KB, 5KB/wave

    const int t = threadIdx.x;
    const int wv = t >> 6, lane = t & 63;
    float* sbuf = stage[wv];
    const long wrow0 = (long)blockIdx.x * RPB + (long)wv * WROWS;
    if (wrow0 >= B) return;

    const v2f* __restrict__ w1p = (const v2f*)ws;   // [5][16] neuron-pairs
    const float* __restrict__ smx = ws + 160;
    const float mxmax = ws[192];

    if (wrow0 + WROWS <= B) {
        // ---- coalesced x stage: 640 floats = 160 v4f, intra-wave only ----
        const v4f* xg = (const v4f*)(x + wrow0 * 5);
        v4f* s4 = (v4f*)sbuf;
#pragma unroll
        for (int e = 0; e < 3; ++e) {
            int idx = e * 64 + lane;
            if (idx < (WROWS * 5) / 4) s4[idx] = xg[idx];
        }

        // own 10 x floats back (lane*40B, v2f reads)
        v2f xp[5];
        {
            const v2f* sx = (const v2f*)(sbuf + lane * 10);
#pragma unroll
            for (int e = 0; e < 5; ++e) xp[e] = sx[e];
        }
        const float* xf = (const float*)xp;

        // ---- layer 1: j2-outer (uniform weights amortized over rows) ----
        unsigned m[RPL] = {0u, 0u};
#pragma unroll
        for (int j2 = 0; j2 < 16; ++j2) {
            const v2f wa = w1p[j2], wb = w1p[16 + j2], wc = w1p[32 + j2];
            const v2f wd = w1p[48 + j2], we = w1p[64 + j2];
#pragma unroll
            for (int c = 0; c < RPL; ++c) {
                v2f h = xf[c * 5 + 0] * wa;   // exact per-neuron chain order
                h += xf[c * 5 + 1] * wb;
                h += xf[c * 5 + 2] * wc;
                h += xf[c * 5 + 3] * wd;
                h += xf[c * 5 + 4] * we;
                if (h.x >= 2.0f) m[c] |= (1u << (2 * j2));
                if (h.y >= 2.0f) m[c] |= (1u << (2 * j2 + 1));
            }
        }

        // ---- gates; note whether this lane produced any dense row ----
        bool dense[RPL];
        unsigned m2s[RPL];
        bool any_dense = false;
#pragma unroll
        for (int c = 0; c < RPL; ++c) {
            dense[c] = false;
            m2s[c] = 0u;
            const unsigned mc = m[c];
            if (mc && ((float)__popc(mc) * mxmax >= 1.998f)) {
                float S = 0.0f;
                unsigned mm = mc;
                while (mm) { int i = __ffs(mm) - 1; mm &= mm - 1; S += smx[i]; }
                if (S >= 1.998f) {
                    // dense layer 2: VERBATIM verified ascending set-bit order
                    float h2[32];
#pragma unroll
                    for (int j = 0; j < 32; ++j) h2[j] = 0.0f;
                    mm = mc;
                    while (mm) {
                        const int i = __ffs(mm) - 1;
                        mm &= mm - 1;
                        const float* col = W2 + i;   // W2^T[i][j] == W2[j*32+i]
#pragma unroll
                        for (int j = 0; j < 32; ++j) h2[j] += col[j * 32];
                    }
                    unsigned m2 = 0u;
#pragma unroll
                    for (int j = 0; j < 32; ++j)
                        if (h2[j] >= 2.0f) m2 |= (1u << j);
                    m2s[c] = m2;
                    if (m2) { dense[c] = true; any_dense = true; }
                }
            }
        }

        if (!__any(any_dense)) {
            // ---- common case (~91% of waves): pure-zero coalesced store ----
            v4f z = {0.0f, 0.0f, 0.0f, 0.0f};
            v4f* og = (v4f*)(out + wrow0 * 10);
#pragma unroll
            for (int e = 0; e < 5; ++e)
                og[e * 64 + lane] = z;
        } else {
            // ---- rare: zero-fill LDS, dense lanes overwrite, flush ----
            {
                v4f z = {0.0f, 0.0f, 0.0f, 0.0f};
#pragma unroll
                for (int e = 0; e < 5; ++e) s4[e * 64 + lane] = z;
            }
#pragma unroll
            for (int c = 0; c < RPL; ++c) {
                if (!dense[c]) continue;
                const unsigned m2 = m2s[c];
                unsigned m3 = 0u;
#pragma unroll
                for (int j = 0; j < 16; ++j) {
                    float g = 0.0f;
#pragma unroll
                    for (int i = 0; i < 32; ++i)
                        if ((m2 >> i) & 1u) g += W3[j * 32 + i];
                    if (g >= 2.0f) m3 |= (1u << j);
                }
                float* orow = sbuf + (lane * RPL + c) * 10;
#pragma unroll
                for (int j = 0; j < 10; ++j) {
                    float g = 0.0f;
#pragma unroll
                    for (int i = 0; i < 16; ++i)
                        if ((m3 >> i) & 1u) g += W4[j * 16 + i];
                    orow[j] = (g >= 2.0f) ? 1.0f : 0.0f;
                }
            }
            v4f* og = (v4f*)(out + wrow0 * 10);
            const v4f* s4c = (const v4f*)sbuf;
#pragma unroll
            for (int e = 0; e < 5; ++e)
                og[e * 64 + lane] = s4c[e * 64 + lane];
        }
    } else {
        // ---- tail (not hit at B=2^21; correctness-general) ----
        for (int c = 0; c < RPL; ++c) {
            const long r = wrow0 + (long)lane * RPL + c;
            if (r >= B) continue;
            float xr[5];
#pragma unroll
            for (int k = 0; k < 5; ++k) xr[k] = x[r * 5 + k];
            unsigned mc = 0u;
#pragma unroll
            for (int j2 = 0; j2 < 16; ++j2) {
                v2f h = xr[0] * w1p[j2];
                h += xr[1] * w1p[16 + j2];
                h += xr[2] * w1p[32 + j2];
                h += xr[3] * w1p[48 + j2];
                h += xr[4] * w1p[64 + j2];
                if (h.x >= 2.0f) mc |= (1u << (2 * j2));
                if (h.y >= 2.0f) mc |= (1u << (2 * j2 + 1));
            }
            float o[10];
#pragma unroll
            for (int j = 0; j < 10; ++j) o[j] = 0.0f;
            if (mc && ((float)__popc(mc) * mxmax >= 1.998f)) {
                float S = 0.0f;
                unsigned mm = mc;
                while (mm) { int i = __ffs(mm) - 1; mm &= mm - 1; S += smx[i]; }
                if (S >= 1.998f) {
                    float h2[32];
#pragma unroll
                    for (int j = 0; j < 32; ++j) h2[j] = 0.0f;
                    mm = mc;
                    while (mm) {
                        const int i = __ffs(mm) - 1;
                        mm &= mm - 1;
                        const float* col = W2 + i;
#pragma unroll
                        for (int j = 0; j < 32; ++j) h2[j] += col[j * 32];
                    }
                    unsigned m2 = 0u;
#pragma unroll
                    for (int j = 0; j < 32; ++j)
                        if (h2[j] >= 2.0f) m2 |= (1u << j);
                    if (m2) {
                        unsigned m3 = 0u;
#pragma unroll
                        for (int j = 0; j < 16; ++j) {
                            float g = 0.0f;
#pragma unroll
                            for (int i = 0; i < 32; ++i)
                                if ((m2 >> i) & 1u) g += W3[j * 32 + i];
                            if (g >= 2.0f) m3 |= (1u << j);
                        }
#pragma unroll
                        for (int j = 0; j < 10; ++j) {
                            float g = 0.0f;
#pragma unroll
                            for (int i = 0; i < 16; ++i)
                                if ((m3 >> i) & 1u) g += W4[j * 16 + i];
                            o[j] = (g >= 2.0f) ? 1.0f : 0.0f;
                        }
                    }
                }
            }
#pragma unroll
            for (int j = 0; j < 10; ++j) out[r * 10 + j] = o[j];
        }
    }
}

extern "C" void kernel_launch(void* const* d_in, const int* in_sizes, int n_in,
                              void* d_out, int out_size, void* d_ws, size_t ws_size,
                              hipStream_t stream) {
    const float* x  = (const float*)d_in[0];
    const float* W1 = (const float*)d_in[1];
    const float* W2 = (const float*)d_in[2];
    const float* W3 = (const float*)d_in[3];
    const float* W4 = (const float*)d_in[4];
    float* out = (float*)d_out;
    float* ws  = (float*)d_ws;

    int B = in_sizes[0] / 5;
    snn_prep<<<1, 64, 0, stream>>>(W1, W2, ws);
    int grid = (B + RPB - 1) / RPB;
    snn_fused<<<grid, TPB, 0, stream>>>(x, W2, W3, W4, ws, out, B);
}